// Round 8
// baseline (85.547 us; speedup 1.0000x reference)
//
#include <hip/hip_runtime.h>
#include <math.h>

// ColBERT pairwise late-interaction score — single fused kernel (R8).
//
// out[b,o] = scale/sqrt(Lq*Lk) * sum_i log(sum_j exp(alpha*qn[b,i].kn[o,j]))/alpha
// Row b is exactly zero if any q_mask[b,i] (reference isfinite guard) -> only
// M ~ 2-3 of 64 b's are live; dead rows zeroed directly by wave 0.
//
// R8 = R7 with the norm phases folded into staging:
//   * During the k/q convert loops, each HALF-WAVE covers exactly one matrix
//     row per unroll step (row = 8r + 2w + (lane>>5), col = lane&31), so row
//     sum-of-squares is a 5-step xor-shuffle reduce in registers — the
//     dedicated k-norm LDS pass (16 ds_read_b128 + ~270 VALU/thread) and the
//     q-norm phase (+1 barrier) are deleted. Norms are now fp32-exact
//     (computed before f16 quantization).
//   * All 32 k float4 loads issue up front (kv[32], ~128 VGPRs, fine at
//     1 wave/SIMD) -> one HBM latency window instead of two.
//
// Numerics: S <= 1 (cosine) -> alpha*S <= 12, exp never overflows; masked j
// add -1e30 before exp -> exact 0; valid j >= e^-12 so rowsum == 0 iff row
// fully k-masked (-inf -> zero). f16 input rounding ~1e-3 vs 5.1e-2 threshold.

#define ALPHA 12.0f

constexpr int B_  = 64;
constexpr int LQ  = 32;
constexpr int O_  = 128;
constexpr int LK  = 256;
constexpr int D_  = 128;
constexpr int LDH = D_ + 8;        // f16 row stride 136 (272 B), 16B-aligned

typedef _Float16 half8   __attribute__((ext_vector_type(8)));
typedef _Float16 half4_t __attribute__((ext_vector_type(4)));
typedef float    f32x4   __attribute__((ext_vector_type(4)));

__device__ __forceinline__ float half_reduce32(float v) {
    // sum within each 32-lane half of the wave (xor 1..16; DPP-friendly)
    v += __shfl_xor(v, 1);
    v += __shfl_xor(v, 2);
    v += __shfl_xor(v, 4);
    v += __shfl_xor(v, 8);
    v += __shfl_xor(v, 16);
    return v;
}

__global__ __launch_bounds__(256, 1)
void colbert_fused_kernel(const float* __restrict__ q,       // [B, Lq, D]
                          const float* __restrict__ k,       // [O, Lk, D]
                          const int*  __restrict__ q_mask,   // [B, Lq] 0/1
                          const int*  __restrict__ k_mask,   // [O, Lk] 0/1
                          const float* __restrict__ logit_scale,
                          float* __restrict__ out)           // [B, O]
{
    __shared__ _Float16 kl[LK][LDH];        // 69632 B
    __shared__ _Float16 ql2[2][LQ][LDH];    // 17408 B (pair of q tiles)
    __shared__ float rk[LK];                // 1/||k_j||  (fp32-exact)
    __shared__ float bjs[LK];               // 0 or -1e30
    __shared__ float rqa2[2][LQ];           // ALPHA/||q_i||
    __shared__ float part2[2][2][LQ];       // [pair][col-half][row]
    __shared__ int   lbm[B_ + 1];           // [0]=M, [1+m]=live b

    const int o     = blockIdx.x;
    const int t     = threadIdx.x;
    const int lane  = t & 63;
    const int w     = t >> 6;
    const int row16 = lane & 15;
    const int quad  = lane >> 4;

    // ---- wave 0 ONLY: q_mask scan + ballot + dead-row zeroing ----
    if (w == 0) {
        const int4* qm4 = (const int4*)q_mask;     // [64][32] ints, lane = b
        int4 mm[8];
        #pragma unroll
        for (int u = 0; u < 8; ++u)
            mm[u] = qm4[lane * 8 + u];
        int any = 0;
        #pragma unroll
        for (int u = 0; u < 8; ++u)
            any |= mm[u].x | mm[u].y | mm[u].z | mm[u].w;
        const bool live = (any == 0);
        unsigned long long mb = __ballot(live);
        if (live) {
            int rank = __popcll(mb & ((1ull << lane) - 1ull));
            lbm[1 + rank] = lane;
        } else {
            out[lane * O_ + o] = 0.0f;             // dead row -> exact zero
        }
        if (lane == 0) lbm[0] = (int)__popcll(mb);
    }

    // ---- all waves: issue ALL 32 k float4 loads up front ----
    const float4* kg = (const float4*)(k + (size_t)o * LK * D_);
    float4 kv[32];
    #pragma unroll
    for (int r = 0; r < 32; ++r)
        kv[r] = kg[t + 256 * r];                   // [256][32] float4, coalesced
    const int   km = k_mask[o * LK + t];           // row j = t
    const float ls = logit_scale[0];

    // ---- convert to f16 LDS + in-register row norms (no read-back pass) ----
    bjs[t] = (km != 0) ? -1e30f : 0.0f;
    #pragma unroll
    for (int r = 0; r < 32; ++r) {
        const int idx = t + 256 * r;
        const int j = idx >> 5, c4 = idx & 31;     // half-wave <-> row j
        half4_t hh;
        hh[0] = (_Float16)kv[r].x; hh[1] = (_Float16)kv[r].y;
        hh[2] = (_Float16)kv[r].z; hh[3] = (_Float16)kv[r].w;
        *(half4_t*)&kl[j][c4 * 4] = hh;
        float sq = kv[r].x * kv[r].x + kv[r].y * kv[r].y
                 + kv[r].z * kv[r].z + kv[r].w * kv[r].w;
        sq = half_reduce32(sq);
        if ((lane & 31) == 0)
            rk[j] = 1.0f / fmaxf(sqrtf(sq), 1e-12f);
    }
    __syncthreads();                               // kl/rk/bjs + lbm visible

    const int M = lbm[0];
    if (M == 0) return;                            // block-uniform

    const float scale  = fminf(__expf(ls), 100.0f);
    const float inv_ln = 1.0f / (sqrtf((float)(LQ * LK)) + 1e-6f);

    // ---- live b's in pairs (B fragments shared across the pair) ----
    for (int midx = 0; midx < M; midx += 2) {
        const int b0 = lbm[1 + midx];
        const int b1 = lbm[1 + ((midx + 1 < M) ? midx + 1 : midx)];

        // q loads for the pair (issued together; tiny, mostly L2/L3-hit)
        const float4* qg0 = (const float4*)(q + (size_t)b0 * LQ * D_);
        const float4* qg1 = (const float4*)(q + (size_t)b1 * LQ * D_);
        float4 qv0[4], qv1[4];
        #pragma unroll
        for (int r = 0; r < 4; ++r) {
            qv0[r] = qg0[t + 256 * r];
            qv1[r] = qg1[t + 256 * r];
        }

        // convert + stage + in-register q norms (same half-wave row trick)
        #pragma unroll
        for (int r = 0; r < 4; ++r) {
            const int idx = t + 256 * r;           // [32][32] float4
            const int i = idx >> 5, c4 = idx & 31;
            half4_t h0, h1;
            h0[0] = (_Float16)qv0[r].x; h0[1] = (_Float16)qv0[r].y;
            h0[2] = (_Float16)qv0[r].z; h0[3] = (_Float16)qv0[r].w;
            h1[0] = (_Float16)qv1[r].x; h1[1] = (_Float16)qv1[r].y;
            h1[2] = (_Float16)qv1[r].z; h1[3] = (_Float16)qv1[r].w;
            *(half4_t*)&ql2[0][i][c4 * 4] = h0;
            *(half4_t*)&ql2[1][i][c4 * 4] = h1;
            float s0 = qv0[r].x * qv0[r].x + qv0[r].y * qv0[r].y
                     + qv0[r].z * qv0[r].z + qv0[r].w * qv0[r].w;
            float s1 = qv1[r].x * qv1[r].x + qv1[r].y * qv1[r].y
                     + qv1[r].z * qv1[r].z + qv1[r].w * qv1[r].w;
            s0 = half_reduce32(s0);
            s1 = half_reduce32(s1);
            if ((lane & 31) == 0) {
                rqa2[0][i] = ALPHA / fmaxf(sqrtf(s0), 1e-12f);
                rqa2[1][i] = ALPHA / fmaxf(sqrtf(s1), 1e-12f);
            }
        }
        __syncthreads();                           // ql2 + rqa2 visible

        // MFMA: wave w -> rows [16*(w>>1), +16), cols [(w&1)*128, +128)
        const int i0 = (w >> 1) * 16;
        const int j0 = (w & 1) * 128;

        half8 afrag[2][4];
        #pragma unroll
        for (int pb = 0; pb < 2; ++pb)
            #pragma unroll
            for (int kk = 0; kk < 4; ++kk)
                afrag[pb][kk] =
                    *(const half8*)&ql2[pb][i0 + row16][kk * 32 + quad * 8];

        float rqv[2][4];
        #pragma unroll
        for (int pb = 0; pb < 2; ++pb)
            #pragma unroll
            for (int rg = 0; rg < 4; ++rg)
                rqv[pb][rg] = rqa2[pb][i0 + quad * 4 + rg];

        float esum[2][4] = {{0.f,0.f,0.f,0.f},{0.f,0.f,0.f,0.f}};
        #pragma unroll
        for (int c = 0; c < 8; ++c) {
            const int jt = j0 + c * 16;
            f32x4 acc0 = {0.f, 0.f, 0.f, 0.f};
            f32x4 acc1 = {0.f, 0.f, 0.f, 0.f};
            #pragma unroll
            for (int kk = 0; kk < 4; ++kk) {
                half8 bfrag =
                    *(const half8*)&kl[jt + row16][kk * 32 + quad * 8];
                acc0 = __builtin_amdgcn_mfma_f32_16x16x32_f16(
                           afrag[0][kk], bfrag, acc0, 0, 0, 0);
                acc1 = __builtin_amdgcn_mfma_f32_16x16x32_f16(
                           afrag[1][kk], bfrag, acc1, 0, 0, 0);
            }
            // C layout: col = lane&15 (j), row = quad*4+reg (i)
            const float rkj = rk[jt + row16];
            const float bb  = bjs[jt + row16];
            #pragma unroll
            for (int rg = 0; rg < 4; ++rg) {
                esum[0][rg] += __expf(acc0[rg] * rqv[0][rg] * rkj + bb);
                esum[1][rg] += __expf(acc1[rg] * rqv[1][rg] * rkj + bb);
            }
        }
        #pragma unroll
        for (int pb = 0; pb < 2; ++pb) {
            #pragma unroll
            for (int rg = 0; rg < 4; ++rg) {
                float e = esum[pb][rg];
                e += __shfl_xor(e, 1);
                e += __shfl_xor(e, 2);
                e += __shfl_xor(e, 4);
                e += __shfl_xor(e, 8);
                esum[pb][rg] = e;
            }
            if (row16 == 0)
                #pragma unroll
                for (int rg = 0; rg < 4; ++rg)
                    part2[pb][w & 1][i0 + quad * 4 + rg] = esum[pb][rg];
        }
        __syncthreads();

        // finalize both pair members: wave 0 (b1==b0 double-write benign)
        if (t < 64) {
            const int pb = t >> 5, i = t & 31;
            float s = part2[pb][0][i] + part2[pb][1][i];
            bool badrow = (s <= 0.f);              // row fully k-masked
            float lse = __logf(fmaxf(s, 1e-38f));
            float tot = lse;
            tot += __shfl_xor(tot, 16);
            tot += __shfl_xor(tot, 8);
            tot += __shfl_xor(tot, 4);
            tot += __shfl_xor(tot, 2);
            tot += __shfl_xor(tot, 1);
            unsigned long long zb = __ballot(badrow);
            if (i == 0) {
                unsigned long long half_mask =
                    (pb == 0) ? 0xFFFFFFFFull : 0xFFFFFFFF00000000ull;
                float res = 0.f;
                if ((zb & half_mask) == 0ull)
                    res = (tot * (1.0f / ALPHA)) * inv_ln * scale;
                out[((pb == 0) ? b0 : b1) * O_ + o] = res;
            }
        }
        // next-iter ql2 writes are gated by the post-staging barrier; part2
        // is re-written only after the next barrier — same structure as R7.
    }
}

extern "C" void kernel_launch(void* const* d_in, const int* in_sizes, int n_in,
                              void* d_out, int out_size, void* d_ws, size_t ws_size,
                              hipStream_t stream) {
    const float* q           = (const float*)d_in[0];
    const float* k           = (const float*)d_in[1];
    const int*   q_mask      = (const int*)d_in[2];
    const int*   k_mask      = (const int*)d_in[3];
    const float* logit_scale = (const float*)d_in[4];
    float* out = (float*)d_out;

    colbert_fused_kernel<<<O_, 256, 0, stream>>>(q, k, q_mask, k_mask,
                                                 logit_scale, out);
}

// Round 9
// 75.274 us; speedup vs baseline: 1.1365x; 1.1365x over previous
//
#include <hip/hip_runtime.h>
#include <math.h>

// ColBERT pairwise late-interaction score — single fused kernel (R9 = revert
// to R7, the best measured: 75.3 us total, kernel ~11.3 us).
//
// R8 (kv[32] upfront + in-staging shuffle norms) regressed +10 us: 128 VGPRs
// of k staging spilled to scratch, and 160 ds_swizzle-class shuffle ops per
// thread in the staging loop added more LDS-pipe traffic than the norm pass
// they replaced. Both reverted.
//
// out[b,o] = scale/sqrt(Lq*Lk) * sum_i log(sum_j exp(alpha*qn[b,i].kn[o,j]))/alpha
// Row b is exactly zero if any q_mask[b,i] (reference isfinite guard) -> only
// M ~ 2-3 of 64 b's are live.
//
// Structure: grid = 128 blocks, one per o.
//   1. ONLY wave 0 reads q_mask (8 KB scattered); waves 1-3 issue k loads
//      immediately. Wave 0 publishes {M, live list} via LDS at the k barrier.
//   2. q[b0]/q[b1] global loads issue BEFORE the k-norm phase (latency hides
//      under norm DS/VALU work).
//   3. Live b's processed in pairs: one B-fragment read feeds two MFMAs.
//
// Numerics: S <= 1 (cosine) -> alpha*S <= 12, exp never overflows; masked j
// add -1e30 before exp -> exact 0; valid j >= e^-12 so rowsum == 0 iff row
// fully k-masked (-inf -> zero). f16 input rounding ~1e-3 vs 5.1e-2 threshold.

#define ALPHA 12.0f

constexpr int B_  = 64;
constexpr int LQ  = 32;
constexpr int O_  = 128;
constexpr int LK  = 256;
constexpr int D_  = 128;
constexpr int LDH = D_ + 8;        // f16 row stride 136 (272 B), 16B-aligned

typedef _Float16 half8   __attribute__((ext_vector_type(8)));
typedef _Float16 half4_t __attribute__((ext_vector_type(4)));
typedef float    f32x4   __attribute__((ext_vector_type(4)));

__global__ __launch_bounds__(256, 1)
void colbert_fused_kernel(const float* __restrict__ q,       // [B, Lq, D]
                          const float* __restrict__ k,       // [O, Lk, D]
                          const int*  __restrict__ q_mask,   // [B, Lq] 0/1
                          const int*  __restrict__ k_mask,   // [O, Lk] 0/1
                          const float* __restrict__ logit_scale,
                          float* __restrict__ out)           // [B, O]
{
    __shared__ _Float16 kl[LK][LDH];        // 69632 B
    __shared__ _Float16 ql2[2][LQ][LDH];    // 17408 B (pair of q tiles)
    __shared__ float rk[LK];                // 1/||k_j||
    __shared__ float bjs[LK];               // 0 or -1e30
    __shared__ float rqa2[2][LQ];           // ALPHA/||q_i||
    __shared__ float part2[2][2][LQ];       // [pair][col-half][row]
    __shared__ int   lbm[B_ + 1];           // [0]=M, [1+m]=live b

    const int o     = blockIdx.x;
    const int t     = threadIdx.x;
    const int lane  = t & 63;
    const int w     = t >> 6;
    const int row16 = lane & 15;
    const int quad  = lane >> 4;

    // ---- wave 0 ONLY: q_mask scan + ballot + dead-row zeroing ----
    if (w == 0) {
        const int4* qm4 = (const int4*)q_mask;     // [64][32] ints, lane = b
        int4 mm[8];
        #pragma unroll
        for (int u = 0; u < 8; ++u)
            mm[u] = qm4[lane * 8 + u];
        int any = 0;
        #pragma unroll
        for (int u = 0; u < 8; ++u)
            any |= mm[u].x | mm[u].y | mm[u].z | mm[u].w;
        const bool live = (any == 0);
        unsigned long long mb = __ballot(live);
        if (live) {
            int rank = __popcll(mb & ((1ull << lane) - 1ull));
            lbm[1 + rank] = lane;
        } else {
            out[lane * O_ + o] = 0.0f;             // dead row -> exact zero
        }
        if (lane == 0) lbm[0] = (int)__popcll(mb);
    }

    // ---- all waves: k tile loads (waves 1-3 start here immediately) ----
    const float4* kg = (const float4*)(k + (size_t)o * LK * D_);
    float4 kv[16];
    #pragma unroll
    for (int r = 0; r < 16; ++r)
        kv[r] = kg[t + 256 * r];                   // rows 0..127, coalesced
    const int   km = k_mask[o * LK + t];           // row j = t
    const float ls = logit_scale[0];

    // convert half 0, load+convert half 1
    #pragma unroll
    for (int r = 0; r < 16; ++r) {
        int idx = t + 256 * r;
        int j = idx >> 5, c4 = idx & 31;
        half4_t hh;
        hh[0] = (_Float16)kv[r].x; hh[1] = (_Float16)kv[r].y;
        hh[2] = (_Float16)kv[r].z; hh[3] = (_Float16)kv[r].w;
        *(half4_t*)&kl[j][c4 * 4] = hh;
    }
    #pragma unroll
    for (int r = 0; r < 16; ++r)
        kv[r] = kg[4096 + t + 256 * r];            // rows 128..255
    #pragma unroll
    for (int r = 0; r < 16; ++r) {
        int idx = 4096 + t + 256 * r;
        int j = idx >> 5, c4 = idx & 31;
        half4_t hh;
        hh[0] = (_Float16)kv[r].x; hh[1] = (_Float16)kv[r].y;
        hh[2] = (_Float16)kv[r].z; hh[3] = (_Float16)kv[r].w;
        *(half4_t*)&kl[j][c4 * 4] = hh;
    }
    __syncthreads();                               // kl + lbm visible

    const int M = lbm[0];
    if (M == 0) return;                            // block-uniform

    const float scale  = fminf(__expf(ls), 100.0f);
    const float inv_ln = 1.0f / (sqrtf((float)(LQ * LK)) + 1e-6f);

    // ---- live b's in pairs; iteration 0 overlaps q loads with k norms ----
    int midx = 0;
    bool first = true;
    while (midx < M) {
        const int b0 = lbm[1 + midx];
        const int b1 = lbm[1 + ((midx + 1 < M) ? midx + 1 : midx)];
        midx += 2;

        // issue q[b0], q[b1] global loads FIRST (latency hides under norms)
        const float4* qg0 = (const float4*)(q + (size_t)b0 * LQ * D_);
        const float4* qg1 = (const float4*)(q + (size_t)b1 * LQ * D_);
        float4 qv0[4], qv1[4];
        #pragma unroll
        for (int r = 0; r < 4; ++r) {
            qv0[r] = qg0[t + 256 * r];
            qv1[r] = qg1[t + 256 * r];
        }

        // k norms + mask bias on iteration 0 (DS/VALU while q in flight)
        if (first) {
            float ss = 0.f;
            #pragma unroll
            for (int p = 0; p < 16; ++p) {
                half8 hh = *(const half8*)&kl[t][p * 8];
                #pragma unroll
                for (int e = 0; e < 8; ++e) {
                    float x = (float)hh[e];
                    ss = fmaf(x, x, ss);
                }
            }
            rk[t]  = 1.0f / fmaxf(sqrtf(ss), 1e-12f);
            bjs[t] = (km != 0) ? -1e30f : 0.0f;
            first = false;
        }

        // convert + stage q pair
        #pragma unroll
        for (int r = 0; r < 4; ++r) {
            int idx = t + 256 * r;                 // [32][32] float4
            int i = idx >> 5, c4 = idx & 31;
            half4_t h0, h1;
            h0[0] = (_Float16)qv0[r].x; h0[1] = (_Float16)qv0[r].y;
            h0[2] = (_Float16)qv0[r].z; h0[3] = (_Float16)qv0[r].w;
            h1[0] = (_Float16)qv1[r].x; h1[1] = (_Float16)qv1[r].y;
            h1[2] = (_Float16)qv1[r].z; h1[3] = (_Float16)qv1[r].w;
            *(half4_t*)&ql2[0][i][c4 * 4] = h0;
            *(half4_t*)&ql2[1][i][c4 * 4] = h1;
        }
        __syncthreads();                           // ql2 + rk/bjs visible

        // q norms: t<64 covers both pair members (pb = t>>5, i = t&31)
        if (t < 64) {
            const int pb = t >> 5, i = t & 31;
            float ss = 0.f;
            #pragma unroll
            for (int p = 0; p < 16; ++p) {
                half8 hh = *(const half8*)&ql2[pb][i][p * 8];
                #pragma unroll
                for (int e = 0; e < 8; ++e) {
                    float x = (float)hh[e];
                    ss = fmaf(x, x, ss);
                }
            }
            rqa2[pb][i] = ALPHA / fmaxf(sqrtf(ss), 1e-12f);
        }
        __syncthreads();

        // MFMA: wave w -> rows [16*(w>>1), +16), cols [(w&1)*128, +128)
        const int i0 = (w >> 1) * 16;
        const int j0 = (w & 1) * 128;

        half8 afrag[2][4];
        #pragma unroll
        for (int pb = 0; pb < 2; ++pb)
            #pragma unroll
            for (int kk = 0; kk < 4; ++kk)
                afrag[pb][kk] =
                    *(const half8*)&ql2[pb][i0 + row16][kk * 32 + quad * 8];

        float rqv[2][4];
        #pragma unroll
        for (int pb = 0; pb < 2; ++pb)
            #pragma unroll
            for (int rg = 0; rg < 4; ++rg)
                rqv[pb][rg] = rqa2[pb][i0 + quad * 4 + rg];

        float esum[2][4] = {{0.f,0.f,0.f,0.f},{0.f,0.f,0.f,0.f}};
        #pragma unroll
        for (int c = 0; c < 8; ++c) {
            const int jt = j0 + c * 16;
            f32x4 acc0 = {0.f, 0.f, 0.f, 0.f};
            f32x4 acc1 = {0.f, 0.f, 0.f, 0.f};
            #pragma unroll
            for (int kk = 0; kk < 4; ++kk) {
                half8 bfrag =
                    *(const half8*)&kl[jt + row16][kk * 32 + quad * 8];
                acc0 = __builtin_amdgcn_mfma_f32_16x16x32_f16(
                           afrag[0][kk], bfrag, acc0, 0, 0, 0);
                acc1 = __builtin_amdgcn_mfma_f32_16x16x32_f16(
                           afrag[1][kk], bfrag, acc1, 0, 0, 0);
            }
            // C layout: col = lane&15 (j), row = quad*4+reg (i)
            const float rkj = rk[jt + row16];
            const float bb  = bjs[jt + row16];
            #pragma unroll
            for (int rg = 0; rg < 4; ++rg) {
                esum[0][rg] += __expf(acc0[rg] * rqv[0][rg] * rkj + bb);
                esum[1][rg] += __expf(acc1[rg] * rqv[1][rg] * rkj + bb);
            }
        }
        #pragma unroll
        for (int pb = 0; pb < 2; ++pb) {
            #pragma unroll
            for (int rg = 0; rg < 4; ++rg) {
                float e = esum[pb][rg];
                e += __shfl_xor(e, 1);
                e += __shfl_xor(e, 2);
                e += __shfl_xor(e, 4);
                e += __shfl_xor(e, 8);
                esum[pb][rg] = e;
            }
            if (row16 == 0)
                #pragma unroll
                for (int rg = 0; rg < 4; ++rg)
                    part2[pb][w & 1][i0 + quad * 4 + rg] = esum[pb][rg];
        }
        __syncthreads();

        // finalize both pair members: wave 0 (b1==b0 double-write benign)
        if (t < 64) {
            const int pb = t >> 5, i = t & 31;
            float s = part2[pb][0][i] + part2[pb][1][i];
            bool badrow = (s <= 0.f);              // row fully k-masked
            float lse = __logf(fmaxf(s, 1e-38f));
            float tot = lse;
            tot += __shfl_xor(tot, 16);
            tot += __shfl_xor(tot, 8);
            tot += __shfl_xor(tot, 4);
            tot += __shfl_xor(tot, 2);
            tot += __shfl_xor(tot, 1);
            unsigned long long zb = __ballot(badrow);
            if (i == 0) {
                unsigned long long half_mask =
                    (pb == 0) ? 0xFFFFFFFFull : 0xFFFFFFFF00000000ull;
                float res = 0.f;
                if ((zb & half_mask) == 0ull)
                    res = (tot * (1.0f / ALPHA)) * inv_ln * scale;
                out[((pb == 0) ? b0 : b1) * O_ + o] = res;
            }
        }
        // next-iter ql2 writes are gated by the post-staging barrier — same
        // protection structure as R6/R7.
    }
}

extern "C" void kernel_launch(void* const* d_in, const int* in_sizes, int n_in,
                              void* d_out, int out_size, void* d_ws, size_t ws_size,
                              hipStream_t stream) {
    const float* q           = (const float*)d_in[0];
    const float* k           = (const float*)d_in[1];
    const int*   q_mask      = (const int*)d_in[2];
    const int*   k_mask      = (const int*)d_in[3];
    const float* logit_scale = (const float*)d_in[4];
    float* out = (float*)d_out;

    colbert_fused_kernel<<<O_, 256, 0, stream>>>(q, k, q_mask, k_mask,
                                                 logit_scale, out);
}